// Round 1
// 107.427 us; speedup vs baseline: 1.0018x; 1.0018x over previous
//
#include <hip/hip_runtime.h>
#include <hip/hip_bf16.h>

namespace {

constexpr int Bn = 2, Sn = 2048, Hn = 16, Dn = 128;
constexpr int QBLK = 128;   // 2 groups x 4 waves x 32 queries
constexpr int KVBLK = 32;   // keys per chunk; superstep = 2 chunks (even/odd group)
constexpr int RS = Hn * Dn; // 2048 floats
constexpr float QSCALE = 0.08838834764831845f * 1.4426950408889634f; // 1/sqrt(D)*log2(e)

typedef __bf16 bf16x8 __attribute__((ext_vector_type(8)));
typedef __bf16 bf16x2 __attribute__((ext_vector_type(2)));
typedef float  f32x16 __attribute__((ext_vector_type(16)));

__device__ __forceinline__ f32x16 mfma32(bf16x8 a, bf16x8 b, f32x16 c) {
  return __builtin_amdgcn_mfma_f32_32x32x16_bf16(a, b, c, 0, 0, 0);
}
__device__ __forceinline__ unsigned pack2(float a, float b) {
  union { __bf16 h[2]; unsigned u; } r;
  r.h[0] = (__bf16)a; r.h[1] = (__bf16)b;
  return r.u;
}
__device__ __forceinline__ float pair_max(float x) { return fmaxf(x, __shfl_xor(x, 32)); }
__device__ __forceinline__ float pair_sum(float x) { return x + __shfl_xor(x, 32); }
__device__ __forceinline__ float f4e(const float4& v, int j) {
  return j == 0 ? v.x : j == 1 ? v.y : j == 2 ? v.z : v.w;
}
__device__ __forceinline__ float lane_bcast(int row, float v) {
  return __uint_as_float(__builtin_amdgcn_ds_bpermute(row * 4, __float_as_uint(v)));
}

// T4 barrier: publish LDS (lgkmcnt(0)) but leave this wave's in-flight
// global_load prefetches (register-destined, private) UN-drained across the
// barrier. __syncthreads() would emit s_waitcnt vmcnt(0) and convoy all 16
// waves on just-issued loads every superstep. The compiler still inserts
// counted vmcnt waits where kr/vr are consumed next iteration.
__device__ __forceinline__ void pipeline_barrier() {
  __builtin_amdgcn_sched_barrier(0);
  asm volatile("s_waitcnt lgkmcnt(0)" ::: "memory");
  __builtin_amdgcn_s_barrier();
  __builtin_amdgcn_sched_barrier(0);
}

// 512 blocks, ONE q-tile each; LDS = 80 KB exactly -> 2 blocks/CU.
// Mapping (from r5, verified): same-XCD heads, co-resident pair (bid, bid+256)
// = tiles (15-s2, s2) -> balanced per-CU work. Inner loop = r8's verified
// S-pipeline: QK^T(t+1) issues on the MFMA pipe, softmax(t)+PV(t) overlap it.
// K ring-6 (chunks 2t..2t+5 live), V ring-4.
__global__ __launch_bounds__(512)
void fa_fwd(const float* __restrict__ Q, const float* __restrict__ K,
            const float* __restrict__ V, float* __restrict__ O)
{
  __shared__ __align__(16) __bf16 Klds[6][KVBLK * 128]; // 48 KB, ring by chunk %6
  __shared__ __align__(16) __bf16 Vt[4][128 * KVBLK];   // 32 KB, ring by chunk &3

  const int tid  = threadIdx.x;
  const int lane = tid & 63;
  const int wave = tid >> 6;
  const int col  = lane & 31;
  const int hi   = lane >> 5;
  const int grp  = wave >> 2;   // 0: even chunks, 1: odd chunks
  const int wq   = wave & 3;

  // r5 mapping: 4 heads per XCD; co-resident pair (bid, bid+256) = (15-s2, s2)
  const int xcd  = (int)blockIdx.x & 7;
  const int s    = (int)blockIdx.x >> 3;    // 0..63
  const int hidx = xcd * 4 + (s & 3);       // 0..31
  const int b    = hidx >> 4, h = hidx & 15;
  const int s2   = s >> 2;                  // 0..15
  const int qt   = (s < 32) ? (15 - s2) : (s2 - 8);
  const int q0w  = qt * QBLK + wq * 32;
  const int T    = 2 * (qt + 1);            // supersteps
  const size_t base = ((size_t)b * Sn) * RS + (size_t)h * Dn;

  // staging coords: threads 0-255 even chunk of superstep, 256-511 odd
  const int sthalf = tid >> 8, ht = tid & 255;
  const int skey = ht >> 3, sd = (ht & 7) * 16;
  const int vkey = (ht & 15) * 2, vd = (ht >> 4) * 8;

  float4 kr[4], vr[4];
  auto loadK = [&](int ss) {
    const int kv0 = (2 * ss + sthalf) * KVBLK;
    const float* kp = K + base + (size_t)(kv0 + skey) * RS + sd;
#pragma unroll
    for (int i = 0; i < 4; ++i) kr[i] = *(const float4*)(kp + 4 * i);
  };
  auto loadV = [&](int ss) {
    const int kv0 = (2 * ss + sthalf) * KVBLK;
    const float* vp = V + base + (size_t)(kv0 + vkey) * RS + vd;
    vr[0] = *(const float4*)(vp);
    vr[1] = *(const float4*)(vp + 4);
    vr[2] = *(const float4*)(vp + RS);
    vr[3] = *(const float4*)(vp + RS + 4);
  };
  auto stageK = [&](int ss) {
    char* kb = (char*)&Klds[(2 * ss + sthalf) % 6][0];
    const int kbase = skey * 256 + sd * 2;
    const int kswz  = (skey & 7) << 4;
#pragma unroll
    for (int i = 0; i < 2; ++i) {
      bf16x8 f;
      f[0] = (__bf16)kr[2*i].x;   f[1] = (__bf16)kr[2*i].y;
      f[2] = (__bf16)kr[2*i].z;   f[3] = (__bf16)kr[2*i].w;
      f[4] = (__bf16)kr[2*i+1].x; f[5] = (__bf16)kr[2*i+1].y;
      f[6] = (__bf16)kr[2*i+1].z; f[7] = (__bf16)kr[2*i+1].w;
      *(bf16x8*)(kb + ((kbase + 16 * i) ^ kswz)) = f;
    }
  };
  auto stageV = [&](int ss) {
    char* vb = (char*)&Vt[(2 * ss + sthalf) & 3][0];
#pragma unroll
    for (int j = 0; j < 8; ++j) {
      const int d = vd + j;
      bf16x2 w;
      w[0] = (__bf16)f4e(vr[j >> 2], j & 3);
      w[1] = (__bf16)f4e(vr[2 + (j >> 2)], j & 3);
      const int addr = (d * 64 + vkey * 2) ^ ((d & 3) << 4) ^ (((d >> 3) & 1) << 6);
      *(bf16x2*)(vb + addr) = w;
    }
  };

  const int cswz = (col & 7) << 4;
  const int vswz = ((col & 3) << 4) ^ (((col >> 3) & 1) << 6);

  // ---- Q fragments, scaled ----
  bf16x8 qf[8];
  {
    const float* qp = Q + base + (size_t)(q0w + col) * RS + hi * 8;
#pragma unroll
    for (int kk = 0; kk < 8; ++kk) {
      float4 a = *(const float4*)(qp + kk * 16);
      float4 c2 = *(const float4*)(qp + kk * 16 + 4);
      bf16x8 f;
      f[0] = (__bf16)(a.x * QSCALE);  f[1] = (__bf16)(a.y * QSCALE);
      f[2] = (__bf16)(a.z * QSCALE);  f[3] = (__bf16)(a.w * QSCALE);
      f[4] = (__bf16)(c2.x * QSCALE); f[5] = (__bf16)(c2.y * QSCALE);
      f[6] = (__bf16)(c2.z * QSCALE); f[7] = (__bf16)(c2.w * QSCALE);
      qf[kk] = f;
    }
  }

  f32x16 o0 = {}, o1 = {}, o2 = {}, o3 = {};
  float m = -1e30f, l = 0.f;

  // ---- prologue: stage K(0),K(1),V(0); issue loads for loop t=0 ----
  loadK(0); loadV(0);
  stageK(0);
  loadK(1);
  stageV(0);
  loadV(1);
  stageK(1);
  if (2 < T) loadK(2);
  pipeline_barrier();           // K0,K1,V0 published; loadK(2) stays in flight

  // S(0)
  f32x16 st_cur = {};
  if (grp * KVBLK <= q0w + 31) {
    const char* kb = (const char*)&Klds[grp][0];
    __builtin_amdgcn_s_setprio(1);
#pragma unroll
    for (int kk = 0; kk < 8; ++kk) {
      bf16x8 ka = *(const bf16x8*)(kb + ((col * 256 + kk * 32 + hi * 16) ^ cswz));
      st_cur = mfma32(ka, qf[kk], st_cur);
    }
    __builtin_amdgcn_s_setprio(0);
  }

#pragma unroll 1
  for (int t = 0; t < T; ++t) {
    // ---- QK^T(t+1): fills the MFMA pipe while softmax(t) runs on VALU ----
    f32x16 stn = {};
    const int icn = 2 * (t + 1) + grp;
    if (t + 1 < T && icn * KVBLK <= q0w + 31) {
      const char* kb = (const char*)&Klds[icn % 6][0];
      __builtin_amdgcn_s_setprio(1);
#pragma unroll
      for (int kk = 0; kk < 8; ++kk) {
        bf16x8 ka = *(const bf16x8*)(kb + ((col * 256 + kk * 32 + hi * 16) ^ cswz));
        stn = mfma32(ka, qf[kk], stn);
      }
      __builtin_amdgcn_s_setprio(0);
    }

    // ---- stage next buffers (consume loads issued last iter), issue new loads ----
    if (t + 2 < T) stageK(t + 2);
    if (t + 1 < T) stageV(t + 1);
    if (t + 3 < T) loadK(t + 3);
    if (t + 2 < T) loadV(t + 2);

    // ---- finish chunk t: mask, softmax, repack, PV ----
    const int kv0 = (2 * t + grp) * KVBLK;
    if (kv0 <= q0w + 31) {
      if (kv0 + KVBLK - 1 > q0w) {
        const int qk = q0w + col - kv0;
#pragma unroll
        for (int r = 0; r < 16; ++r) {
          const int krow = (r & 3) + 8 * (r >> 2) + 4 * hi;
          st_cur[r] = (krow <= qk) ? st_cur[r] : -1e30f;
        }
      }

      float t8[8];
#pragma unroll
      for (int r = 0; r < 8; ++r) t8[r] = fmaxf(st_cur[r], st_cur[r + 8]);
#pragma unroll
      for (int r = 0; r < 4; ++r) t8[r] = fmaxf(t8[r], t8[r + 4]);
      const float pmax = pair_max(fmaxf(fmaxf(t8[0], t8[1]), fmaxf(t8[2], t8[3])));

      if (!__all(pmax <= m + 11.0f)) {   // T13 defer-max
        const float mnew = fmaxf(m, pmax);
        const float al = __builtin_amdgcn_exp2f(m - mnew);
        m = mnew;
        l *= al;
#pragma unroll
        for (int r = 0; r < 16; ++r) {
          const int row = (r & 3) + 8 * (r >> 2) + 4 * hi;
          const float ar = lane_bcast(row, al);
          o0[r] *= ar; o1[r] *= ar; o2[r] *= ar; o3[r] *= ar;
        }
      }

      float s4[4] = {0.f, 0.f, 0.f, 0.f};
#pragma unroll
      for (int r = 0; r < 16; ++r) {
        st_cur[r] = __builtin_amdgcn_exp2f(st_cur[r] - m);
        s4[r & 3] += st_cur[r];
      }
      l += pair_sum((s4[0] + s4[1]) + (s4[2] + s4[3]));

      // P -> A-fragments (pack + 4 cross-half shuffles)
      unsigned cw[8];
#pragma unroll
      for (int i = 0; i < 8; ++i) cw[i] = pack2(st_cur[2 * i], st_cur[2 * i + 1]);
      const unsigned x1 = (unsigned)__shfl_xor((int)(hi ? cw[0] : cw[2]), 32);
      const unsigned x2 = (unsigned)__shfl_xor((int)(hi ? cw[1] : cw[3]), 32);
      const unsigned x3 = (unsigned)__shfl_xor((int)(hi ? cw[4] : cw[6]), 32);
      const unsigned x4 = (unsigned)__shfl_xor((int)(hi ? cw[5] : cw[7]), 32);
      union { unsigned u[4]; bf16x8 v; } pa0, pa1;
      pa0.u[0] = hi ? x1 : cw[0];  pa0.u[1] = hi ? x2 : cw[1];
      pa0.u[2] = hi ? cw[2] : x1;  pa0.u[3] = hi ? cw[3] : x2;
      pa1.u[0] = hi ? x3 : cw[4];  pa1.u[1] = hi ? x4 : cw[5];
      pa1.u[2] = hi ? cw[6] : x3;  pa1.u[3] = hi ? cw[7] : x4;

      const char* vb = (const char*)&Vt[(2 * t + grp) & 3][0];
      __builtin_amdgcn_s_setprio(1);
#pragma unroll
      for (int ks = 0; ks < 2; ++ks) {
        const bf16x8 pa = ks ? pa1.v : pa0.v;
#define PV_STEP(ovar, dt) { \
        bf16x8 vf = *(const bf16x8*)(vb + ((((dt)*32 + col) * 64 + ks * 32 + hi * 16) ^ vswz)); \
        ovar = mfma32(pa, vf, ovar); }
        PV_STEP(o0, 0) PV_STEP(o1, 1) PV_STEP(o2, 2) PV_STEP(o3, 3)
#undef PV_STEP
      }
      __builtin_amdgcn_s_setprio(0);
    }
    pipeline_barrier();   // publish stage writes; prefetch loads stay in flight
    st_cur = stn;
  }

  // ---- merge group-1 partials into group-0 (LDS scratch over K/V buffers) ----
  float* ob  = reinterpret_cast<float*>(&Klds[0][0]);   // 8192 floats (32 KB)
  float* mlb = reinterpret_cast<float*>(&Vt[0][0]);
  if (grp == 1) {
    mlb[wq * 128 + lane] = m;
    mlb[wq * 128 + 64 + lane] = l;
#pragma unroll
    for (int r = 0; r < 16; ++r) {
      ob[wq * 1024 + r * 64 + lane] = o0[r];
      ob[4096 + wq * 1024 + r * 64 + lane] = o1[r];
    }
  }
  __syncthreads();
  float f0 = 1.f, f1 = 0.f;
  if (grp == 0) {
    const float m1 = mlb[wq * 128 + lane];
    const float l1 = mlb[wq * 128 + 64 + lane];
    const float mS = fmaxf(m, m1);
    f0 = __builtin_amdgcn_exp2f(m - mS);
    f1 = __builtin_amdgcn_exp2f(m1 - mS);
    l = l * f0 + l1 * f1;
#pragma unroll
    for (int r = 0; r < 16; ++r) {
      const int row = (r & 3) + 8 * (r >> 2) + 4 * hi;
      const float a0 = lane_bcast(row, f0), a1 = lane_bcast(row, f1);
      o0[r] = o0[r] * a0 + ob[wq * 1024 + r * 64 + lane] * a1;
      o1[r] = o1[r] * a0 + ob[4096 + wq * 1024 + r * 64 + lane] * a1;
    }
  }
  __syncthreads();
  if (grp == 1) {
#pragma unroll
    for (int r = 0; r < 16; ++r) {
      ob[wq * 1024 + r * 64 + lane] = o2[r];
      ob[4096 + wq * 1024 + r * 64 + lane] = o3[r];
    }
  }
  __syncthreads();
  if (grp == 0) {
#pragma unroll
    for (int r = 0; r < 16; ++r) {
      const int row = (r & 3) + 8 * (r >> 2) + 4 * hi;
      const float a0 = lane_bcast(row, f0), a1 = lane_bcast(row, f1);
      o2[r] = o2[r] * a0 + ob[wq * 1024 + r * 64 + lane] * a1;
      o3[r] = o3[r] * a0 + ob[4096 + wq * 1024 + r * 64 + lane] * a1;
    }
    // ---- epilogue: store ----
    const float linv = 1.0f / l;
#pragma unroll
    for (int r = 0; r < 16; ++r) {
      const int row = (r & 3) + 8 * (r >> 2) + 4 * hi;
      const float lr = lane_bcast(row, linv);
      float* op = O + base + (size_t)(q0w + row) * RS + col;
      op[0]  = o0[r] * lr;
      op[32] = o1[r] * lr;
      op[64] = o2[r] * lr;
      op[96] = o3[r] * lr;
    }
  }
}

} // namespace

extern "C" void kernel_launch(void* const* d_in, const int* /*in_sizes*/, int /*n_in*/,
                              void* d_out, int /*out_size*/, void* /*d_ws*/, size_t /*ws_size*/,
                              hipStream_t stream) {
  const float* q = (const float*)d_in[0];
  const float* k = (const float*)d_in[1];
  const float* v = (const float*)d_in[2];
  float* o = (float*)d_out;
  dim3 grid(Bn * Hn * (Sn / QBLK));   // 512 blocks, 2 per CU (80 KB LDS each)
  dim3 blk(512);
  hipLaunchKernelGGL(fa_fwd, grid, blk, 0, stream, q, k, v, o);
}